// Round 3
// baseline (462.376 us; speedup 1.0000x reference)
//
#include <hip/hip_runtime.h>
#include <hip/hip_bf16.h>

// EquivariantLayerNorm: segmented (per-block) LayerNorm over H and edge_attr,
// plus equivariant coordinate rescale on Z.
//
// Inputs (setup_inputs order, all f32 except ids):
//  0: H        [N,128]   1: Z       [N,3]    2: edge_attr [E,64]
//  3: sigma    [1,3]     4: ln_H_w  [128]    5: ln_H_b    [128]
//  6: ln_E_w   [64]      7: ln_E_b  [64]     8: block_id  [N] (sorted i32)
//  9: edge_id  [2,E] i32
// Output: concat(H_out [N*128], Z_out [N*3], E_out [E*64], rescale [NB*3])

#define EPS_LN 1e-12f
#define EPS_STD 1e-8f

__device__ __forceinline__ float4 f4zero() { return make_float4(0.f, 0.f, 0.f, 0.f); }

// ---------- segment offsets from sorted block_id + zero counts --------------
__global__ void node_off_kernel(const int* __restrict__ block_id, int N, int NB,
                                int* __restrict__ node_off, int* __restrict__ count) {
  int i = blockIdx.x * blockDim.x + threadIdx.x;
  if (i < NB) count[i] = 0;
  if (i >= N) return;
  int cur = block_id[i];
  int prev = (i == 0) ? -1 : block_id[i - 1];
  for (int b = prev + 1; b <= cur; ++b) node_off[b] = i;
  if (i == N - 1) {
    for (int b = cur + 1; b <= NB; ++b) node_off[b] = N;
  }
}

// ---------------- node-side: one 256-thread workgroup per block -------------
// 8 node-slots in flight, float4 per lane (32 lane-groups x 4 = 128 features).
__global__ void node_kernel(const float4* __restrict__ H4,
                            const float* __restrict__ Z,
                            const float* __restrict__ sigma,
                            const float* __restrict__ wH,
                            const float* __restrict__ bH,
                            const int* __restrict__ node_off,
                            float4* __restrict__ H_out4,
                            float* __restrict__ Z_out,
                            float* __restrict__ rescale_out) {
  const int b = blockIdx.x;
  const int start = node_off[b], end = node_off[b + 1];
  const int c = end - start;
  const float denom = fmaxf((float)c, 1.0f);
  const int fg = threadIdx.x & 31;    // feature group: floats [fg*4, fg*4+4)
  const int slot = threadIdx.x >> 5;  // node slot 0..7

  // --- H stats (strided over nodes, vectorized over features) ---
  float4 sum = f4zero(), sq = f4zero();
  for (int i = start + slot; i < end; i += 8) {
    float4 x = H4[(size_t)i * 32 + fg];
    sum.x += x.x; sum.y += x.y; sum.z += x.z; sum.w += x.w;
    sq.x = fmaf(x.x, x.x, sq.x); sq.y = fmaf(x.y, x.y, sq.y);
    sq.z = fmaf(x.z, x.z, sq.z); sq.w = fmaf(x.w, x.w, sq.w);
  }
  __shared__ float4 s_sum[8][32];
  __shared__ float4 s_sq[8][32];
  __shared__ float4 s_u[32], s_r[32];
  __shared__ float s_zc[3], s_sd[3], s_sdd[3];
  s_sum[slot][fg] = sum;
  s_sq[slot][fg] = sq;
  __syncthreads();

  if (slot == 0) {  // wave-0 lanes 0..31: cross-slot reduce + u/rstd
    float4 ts = s_sum[0][fg], tq = s_sq[0][fg];
    #pragma unroll
    for (int s = 1; s < 8; ++s) {
      float4 a = s_sum[s][fg], q = s_sq[s][fg];
      ts.x += a.x; ts.y += a.y; ts.z += a.z; ts.w += a.w;
      tq.x += q.x; tq.y += q.y; tq.z += q.z; tq.w += q.w;
    }
    float4 u, r;
    u.x = ts.x / denom; u.y = ts.y / denom; u.z = ts.z / denom; u.w = ts.w / denom;
    r.x = rsqrtf(fmaxf(tq.x / denom - u.x * u.x, 0.f) + EPS_LN);
    r.y = rsqrtf(fmaxf(tq.y / denom - u.y * u.y, 0.f) + EPS_LN);
    r.z = rsqrtf(fmaxf(tq.z / denom - u.z * u.z, 0.f) + EPS_LN);
    r.w = rsqrtf(fmaxf(tq.w / denom - u.w * u.w, 0.f) + EPS_LN);
    s_u[fg] = u;
    s_r[fg] = r;
  }

  // --- Z stats on wave 3 (overlaps the reduce above) ---
  const int zt = threadIdx.x - 192;  // 0..2 handle axis zt
  if (zt >= 0 && zt < 3) {
    float zs = 0.0f;
    for (int i = start; i < end; ++i) zs += Z[(size_t)i * 3 + zt];
    float zc = zs / denom;
    s_zc[zt] = zc;
    float sd = 0.0f, sdd = 0.0f;
    for (int i = start; i < end; ++i) {
      float d = Z[(size_t)i * 3 + zt] - zc;
      sd += d;
      sdd = fmaf(d, d, sdd);
    }
    s_sd[zt] = sd;
    s_sdd[zt] = sdd;
  }
  __syncthreads();

  // --- H output pass ---
  const float4 u = s_u[fg], r = s_r[fg];
  const float4 w = reinterpret_cast<const float4*>(wH)[fg];
  const float4 bb = reinterpret_cast<const float4*>(bH)[fg];
  for (int i = start + slot; i < end; i += 8) {
    float4 x = H4[(size_t)i * 32 + fg];
    float4 o;
    o.x = fmaf(w.x * (x.x - u.x), r.x, bb.x);
    o.y = fmaf(w.y * (x.y - u.y), r.y, bb.y);
    o.z = fmaf(w.z * (x.z - u.z), r.z, bb.z);
    o.w = fmaf(w.w * (x.w - u.w), r.w, bb.w);
    H_out4[(size_t)i * 32 + fg] = o;
  }

  // --- Z rescale + output (threads 192..194) ---
  if (zt >= 0 && zt < 3) {
    const float cnt3 = 3.0f * (float)c;
    const float m = (s_sd[0] + s_sd[1] + s_sd[2]) / fmaxf(cnt3, 1.0f);
    float ss = (s_sdd[0] + s_sdd[1] + s_sdd[2]) - cnt3 * m * m;
    ss = fmaxf(ss, 0.0f);
    const float var_Ez = sqrtf(ss / fmaxf(cnt3 - 1.0f, 1.0f)) + EPS_STD;
    const float resc = sigma[zt] / var_Ez;
    rescale_out[(size_t)b * 3 + zt] = resc;
    const float zc = s_zc[zt];
    for (int i = start; i < end; ++i) {
      float d = Z[(size_t)i * 3 + zt] - zc;
      Z_out[(size_t)i * 3 + zt] = fmaf(d, resc, zc);
    }
  }
}

// ---------------- edge-side: counting sort by segment --------------------
__global__ void edge_seg_kernel(const int* __restrict__ edge_id,
                                const int* __restrict__ block_id, int E,
                                int* __restrict__ seg, int* __restrict__ count) {
  int e = blockIdx.x * blockDim.x + threadIdx.x;
  if (e >= E) return;
  int src = edge_id[e];  // row 0 of edge_id [2,E]
  int s = block_id[src];
  seg[e] = s;
  atomicAdd(&count[s], 1);
}

__global__ void scan_kernel(const int* __restrict__ count, int NB,
                            int* __restrict__ offset, int* __restrict__ cursor) {
  __shared__ int lds[1024];
  const int t = threadIdx.x;
  const int per = (NB + 1023) / 1024;
  const int lo = t * per;
  const int hi = min(lo + per, NB);
  int s = 0;
  for (int i = lo; i < hi; ++i) s += count[i];
  lds[t] = s;
  __syncthreads();
  for (int d = 1; d < 1024; d <<= 1) {
    int v = (t >= d) ? lds[t - d] : 0;
    __syncthreads();
    lds[t] += v;
    __syncthreads();
  }
  int excl = lds[t] - s;
  for (int i = lo; i < hi; ++i) {
    offset[i] = excl;
    cursor[i] = excl;
    excl += count[i];
  }
  if (t == 1023) offset[NB] = lds[1023];
}

__global__ void scatter_kernel(const int* __restrict__ seg, int E,
                               int* __restrict__ cursor, int* __restrict__ order) {
  int e = blockIdx.x * blockDim.x + threadIdx.x;
  if (e >= E) return;
  int pos = atomicAdd(&cursor[seg[e]], 1);
  order[pos] = e;
}

// ---- per-segment edge stats only (u, rstd) -> ur table [NB][16][2] float4 --
#define ELN_CAP 512
__global__ void edge_stats_kernel(const float4* __restrict__ EA4,
                                  const int* __restrict__ offset,
                                  const int* __restrict__ order,
                                  float4* __restrict__ ur_tab) {
  const int b = blockIdx.x;
  const int start = offset[b], end = offset[b + 1];
  const int cnt = end - start;
  const int fg = threadIdx.x & 15;    // feature group: floats [fg*4, fg*4+4)
  const int slot = threadIdx.x >> 4;  // edge slot 0..15

  __shared__ int s_order[ELN_CAP];
  const int lim = min(cnt, ELN_CAP);
  for (int i = threadIdx.x; i < lim; i += 256) s_order[i] = order[start + i];
  __syncthreads();

  float4 sum = f4zero(), sq = f4zero();
  for (int i = slot; i < cnt; i += 16) {
    int e = (i < ELN_CAP) ? s_order[i] : order[start + i];
    float4 x = EA4[(size_t)e * 16 + fg];
    sum.x += x.x; sum.y += x.y; sum.z += x.z; sum.w += x.w;
    sq.x = fmaf(x.x, x.x, sq.x); sq.y = fmaf(x.y, x.y, sq.y);
    sq.z = fmaf(x.z, x.z, sq.z); sq.w = fmaf(x.w, x.w, sq.w);
  }
  __shared__ float4 s_sum[16][16];
  __shared__ float4 s_sq[16][16];
  s_sum[slot][fg] = sum;
  s_sq[slot][fg] = sq;
  __syncthreads();

  if (slot == 0) {
    float4 ts = s_sum[0][fg], tq = s_sq[0][fg];
    #pragma unroll
    for (int s = 1; s < 16; ++s) {
      float4 a = s_sum[s][fg], q = s_sq[s][fg];
      ts.x += a.x; ts.y += a.y; ts.z += a.z; ts.w += a.w;
      tq.x += q.x; tq.y += q.y; tq.z += q.z; tq.w += q.w;
    }
    const float denom = fmaxf((float)cnt, 1.0f);
    float4 u, r;
    u.x = ts.x / denom; u.y = ts.y / denom; u.z = ts.z / denom; u.w = ts.w / denom;
    r.x = rsqrtf(fmaxf(tq.x / denom - u.x * u.x, 0.f) + EPS_LN);
    r.y = rsqrtf(fmaxf(tq.y / denom - u.y * u.y, 0.f) + EPS_LN);
    r.z = rsqrtf(fmaxf(tq.z / denom - u.z * u.z, 0.f) + EPS_LN);
    r.w = rsqrtf(fmaxf(tq.w / denom - u.w * u.w, 0.f) + EPS_LN);
    ur_tab[(size_t)b * 32 + fg * 2] = u;
    ur_tab[(size_t)b * 32 + fg * 2 + 1] = r;
  }
}

// ---- streaming edge output: coalesced read/write, ur gather from L2 --------
__global__ void edge_out_kernel(const float4* __restrict__ EA4,
                                const float* __restrict__ wE,
                                const float* __restrict__ bE,
                                const int* __restrict__ seg,
                                const float4* __restrict__ ur_tab,
                                float4* __restrict__ E_out4, int total4) {
  const int stride = gridDim.x * blockDim.x;     // multiple of 16
  int idx = blockIdx.x * blockDim.x + threadIdx.x;
  if (idx >= total4) return;
  const int fg = idx & 15;                        // constant across iterations
  const float4 w = reinterpret_cast<const float4*>(wE)[fg];
  const float4 bb = reinterpret_cast<const float4*>(bE)[fg];
  for (; idx < total4; idx += stride) {
    const int e = idx >> 4;
    const int s = seg[e];
    float4 x = EA4[idx];
    float4 u = ur_tab[(size_t)s * 32 + fg * 2];
    float4 r = ur_tab[(size_t)s * 32 + fg * 2 + 1];
    float4 o;
    o.x = fmaf(w.x * (x.x - u.x), r.x, bb.x);
    o.y = fmaf(w.y * (x.y - u.y), r.y, bb.y);
    o.z = fmaf(w.z * (x.z - u.z), r.z, bb.z);
    o.w = fmaf(w.w * (x.w - u.w), r.w, bb.w);
    E_out4[idx] = o;
  }
}

extern "C" void kernel_launch(void* const* d_in, const int* in_sizes, int n_in,
                              void* d_out, int out_size, void* d_ws, size_t ws_size,
                              hipStream_t stream) {
  const float* H        = (const float*)d_in[0];
  const float* Z        = (const float*)d_in[1];
  const float* EA       = (const float*)d_in[2];
  const float* sigma    = (const float*)d_in[3];
  const float* ln_H_w   = (const float*)d_in[4];
  const float* ln_H_b   = (const float*)d_in[5];
  const float* ln_E_w   = (const float*)d_in[6];
  const float* ln_E_b   = (const float*)d_in[7];
  const int*   block_id = (const int*)d_in[8];
  const int*   edge_id  = (const int*)d_in[9];

  const int N = in_sizes[0] / 128;
  const int E = in_sizes[2] / 64;
  const int NB = (int)(((long long)out_size - (long long)N * 131 - (long long)E * 64) / 3);

  float* out = (float*)d_out;
  float* H_out = out;
  float* Z_out = out + (size_t)N * 128;
  float* E_out = out + (size_t)N * 128 + (size_t)N * 3;
  float* resc  = out + (size_t)N * 128 + (size_t)N * 3 + (size_t)E * 64;

  // workspace layout
  int* seg      = (int*)d_ws;                   // E
  int* order    = seg + E;                      // E
  int* count    = order + E;                    // NB
  int* offset   = count + NB;                   // NB+1
  int* cursor   = offset + NB + 1;              // NB
  int* node_off = cursor + NB;                  // NB+1
  float4* ur_tab = (float4*)(((uintptr_t)(node_off + NB + 1) + 15) & ~(uintptr_t)15);  // NB*32 float4

  node_off_kernel<<<(N + 255) / 256, 256, 0, stream>>>(block_id, N, NB, node_off, count);
  edge_seg_kernel<<<(E + 255) / 256, 256, 0, stream>>>(edge_id, block_id, E, seg, count);
  node_kernel<<<NB, 256, 0, stream>>>((const float4*)H, Z, sigma, ln_H_w, ln_H_b,
                                      node_off, (float4*)H_out, Z_out, resc);
  scan_kernel<<<1, 1024, 0, stream>>>(count, NB, offset, cursor);
  scatter_kernel<<<(E + 255) / 256, 256, 0, stream>>>(seg, E, cursor, order);
  edge_stats_kernel<<<NB, 256, 0, stream>>>((const float4*)EA, offset, order, ur_tab);
  const int total4 = E * 16;
  edge_out_kernel<<<2048, 256, 0, stream>>>((const float4*)EA, ln_E_w, ln_E_b,
                                            seg, ur_tab, (float4*)E_out, total4);
}

// Round 4
// 322.298 us; speedup vs baseline: 1.4346x; 1.4346x over previous
//
#include <hip/hip_runtime.h>
#include <hip/hip_bf16.h>

// EquivariantLayerNorm: segmented (per-block) LayerNorm over H and edge_attr,
// plus equivariant coordinate rescale on Z.
//
// Inputs (setup_inputs order, all f32 except ids):
//  0: H        [N,128]   1: Z       [N,3]    2: edge_attr [E,64]
//  3: sigma    [1,3]     4: ln_H_w  [128]    5: ln_H_b    [128]
//  6: ln_E_w   [64]      7: ln_E_b  [64]     8: block_id  [N] (sorted i32)
//  9: edge_id  [2,E] i32
// Output: concat(H_out [N*128], Z_out [N*3], E_out [E*64], rescale [NB*3])

#define EPS_LN 1e-12f
#define EPS_STD 1e-8f

__device__ __forceinline__ float4 f4zero() { return make_float4(0.f, 0.f, 0.f, 0.f); }
__device__ __forceinline__ void f4acc(float4& s, float4& q, const float4 x) {
  s.x += x.x; s.y += x.y; s.z += x.z; s.w += x.w;
  q.x = fmaf(x.x, x.x, q.x); q.y = fmaf(x.y, x.y, q.y);
  q.z = fmaf(x.z, x.z, q.z); q.w = fmaf(x.w, x.w, q.w);
}
__device__ __forceinline__ void f4add(float4& a, const float4 b) {
  a.x += b.x; a.y += b.y; a.z += b.z; a.w += b.w;
}
__device__ __forceinline__ void f4shflxor(float4& v, int m) {
  v.x += __shfl_xor(v.x, m); v.y += __shfl_xor(v.y, m);
  v.z += __shfl_xor(v.z, m); v.w += __shfl_xor(v.w, m);
}

// ---------- segment offsets from sorted block_id + zero counts --------------
__global__ void node_off_kernel(const int* __restrict__ block_id, int N, int NB,
                                int* __restrict__ node_off, int* __restrict__ count) {
  int i = blockIdx.x * blockDim.x + threadIdx.x;
  if (i < NB) count[i] = 0;
  if (i >= N) return;
  int cur = block_id[i];
  int prev = (i == 0) ? -1 : block_id[i - 1];
  for (int b = prev + 1; b <= cur; ++b) node_off[b] = i;
  if (i == N - 1) {
    for (int b = cur + 1; b <= NB; ++b) node_off[b] = N;
  }
}

// ---------------- node-side: one 256-thread workgroup per block -------------
// 8 node-slots, float4 per lane (32 fg x 4 = 128 features), 3-deep pipeline.
__global__ void node_kernel(const float4* __restrict__ H4,
                            const float* __restrict__ Z,
                            const float* __restrict__ sigma,
                            const float* __restrict__ wH,
                            const float* __restrict__ bH,
                            const int* __restrict__ node_off,
                            float4* __restrict__ H_out4,
                            float* __restrict__ Z_out,
                            float* __restrict__ rescale_out) {
  const int b = blockIdx.x;
  const int start = node_off[b], end = node_off[b + 1];
  const int c = end - start;
  const float denom = fmaxf((float)c, 1.0f);
  const int fg = threadIdx.x & 31;    // feature group
  const int slot = threadIdx.x >> 5;  // 0..7
  const int wave = threadIdx.x >> 6;  // 0..3
  const int lane = threadIdx.x & 63;

  __shared__ float4 s_psum[4][32];
  __shared__ float4 s_psq[4][32];
  __shared__ float4 s_u[32], s_r[32];
  __shared__ float s_zp[64], s_zq[64];
  __shared__ float s_zc[3], s_resc[3];

  // --- H stats: stride 8 slots, unroll x3 (covers 24 rows/sweep) ---
  float4 sum = f4zero(), sq = f4zero();
  for (int i = start + slot; i < end; i += 24) {
    float4 x0 = H4[(size_t)i * 32 + fg];
    float4 x1 = (i + 8  < end) ? H4[(size_t)(i + 8)  * 32 + fg] : f4zero();
    float4 x2 = (i + 16 < end) ? H4[(size_t)(i + 16) * 32 + fg] : f4zero();
    f4acc(sum, sq, x0); f4acc(sum, sq, x1); f4acc(sum, sq, x2);
  }
  // reduce slot-pair within wave (slot differs in bit5 => lane xor 32)
  f4shflxor(sum, 32); f4shflxor(sq, 32);
  if (lane < 32) { s_psum[wave][fg] = sum; s_psq[wave][fg] = sq; }

  // --- Z single-pass stats: wave 3, 63 coalesced lanes (lane=3k+a) ---
  if (wave == 3 && lane < 63) {
    const float* zbase = Z + (size_t)start * 3;
    const int tot = c * 3;
    float zs = 0.f, zq = 0.f;
    for (int j = lane; j < tot; j += 63) {  // 63 % 3 == 0 -> axis fixed per lane
      float z = zbase[j];
      zs += z; zq = fmaf(z, z, zq);
    }
    s_zp[lane] = zs; s_zq[lane] = zq;
  }
  __syncthreads();

  // --- H reduce (threads 0..31) ---
  if (threadIdx.x < 32) {
    float4 ts = s_psum[0][fg], tq = s_psq[0][fg];
    f4add(ts, s_psum[1][fg]); f4add(ts, s_psum[2][fg]); f4add(ts, s_psum[3][fg]);
    f4add(tq, s_psq[1][fg]);  f4add(tq, s_psq[2][fg]);  f4add(tq, s_psq[3][fg]);
    float4 u, r;
    u.x = ts.x / denom; u.y = ts.y / denom; u.z = ts.z / denom; u.w = ts.w / denom;
    r.x = rsqrtf(fmaxf(tq.x / denom - u.x * u.x, 0.f) + EPS_LN);
    r.y = rsqrtf(fmaxf(tq.y / denom - u.y * u.y, 0.f) + EPS_LN);
    r.z = rsqrtf(fmaxf(tq.z / denom - u.z * u.z, 0.f) + EPS_LN);
    r.w = rsqrtf(fmaxf(tq.w / denom - u.w * u.w, 0.f) + EPS_LN);
    s_u[fg] = u; s_r[fg] = r;
  }
  // --- Z fold + rescale (thread 64, serial over 63 partials) ---
  if (threadIdx.x == 64) {
    float zs[3], zq[3];
    #pragma unroll
    for (int a = 0; a < 3; ++a) {
      float ps = 0.f, pq = 0.f;
      for (int k = a; k < 63; k += 3) { ps += s_zp[k]; pq += s_zq[k]; }
      zs[a] = ps; zq[a] = pq;
    }
    const float cnt3 = 3.0f * (float)c;
    float msum = 0.f, ss = 0.f;
    #pragma unroll
    for (int a = 0; a < 3; ++a) {
      float zc = zs[a] / denom;
      s_zc[a] = zc;
      msum += zs[a] - (float)c * zc;                       // ~0 (fp residue)
      ss += zq[a] - 2.f * zc * zs[a] + (float)c * zc * zc; // sum (z-zc)^2
    }
    const float m = msum / fmaxf(cnt3, 1.0f);
    ss = fmaxf(ss - cnt3 * m * m, 0.f);
    const float var_Ez = sqrtf(ss / fmaxf(cnt3 - 1.0f, 1.0f)) + EPS_STD;
    #pragma unroll
    for (int a = 0; a < 3; ++a) {
      float rc = sigma[a] / var_Ez;
      s_resc[a] = rc;
      rescale_out[(size_t)b * 3 + a] = rc;
    }
  }
  __syncthreads();

  // --- H output pass (all threads, unroll x3, loads hit L1/L2) ---
  {
    const float4 u = s_u[fg], r = s_r[fg];
    const float4 w = reinterpret_cast<const float4*>(wH)[fg];
    const float4 bb = reinterpret_cast<const float4*>(bH)[fg];
    for (int i = start + slot; i < end; i += 24) {
      #pragma unroll
      for (int k = 0; k < 3; ++k) {
        int ii = i + k * 8;
        if (ii < end) {
          float4 x = H4[(size_t)ii * 32 + fg];
          float4 o;
          o.x = fmaf(w.x * (x.x - u.x), r.x, bb.x);
          o.y = fmaf(w.y * (x.y - u.y), r.y, bb.y);
          o.z = fmaf(w.z * (x.z - u.z), r.z, bb.z);
          o.w = fmaf(w.w * (x.w - u.w), r.w, bb.w);
          H_out4[(size_t)ii * 32 + fg] = o;
        }
      }
    }
  }

  // --- Z output (wave 3, coalesced) ---
  if (wave == 3 && lane < 63) {
    const float* zbase = Z + (size_t)start * 3;
    float* zobase = Z_out + (size_t)start * 3;
    const int tot = c * 3;
    const int a = lane % 3;  // stride 63 keeps axis fixed
    const float zc = s_zc[a], rc = s_resc[a];
    for (int j = lane; j < tot; j += 63) {
      float z = zbase[j];
      zobase[j] = fmaf(z - zc, rc, zc);
    }
  }
}

// ---------------- edge-side: counting sort by segment -----------------------
__global__ void edge_seg_kernel(const int* __restrict__ edge_id,
                                const int* __restrict__ block_id, int E,
                                int* __restrict__ seg, int* __restrict__ count) {
  int e = blockIdx.x * blockDim.x + threadIdx.x;
  if (e >= E) return;
  int src = edge_id[e];  // row 0 of edge_id [2,E]
  int s = block_id[src];
  seg[e] = s;
  atomicAdd(&count[s], 1);
}

__global__ void scan_kernel(const int* __restrict__ count, int NB,
                            int* __restrict__ offset, int* __restrict__ cursor) {
  __shared__ int lds[1024];
  const int t = threadIdx.x;
  const int per = (NB + 1023) / 1024;
  const int lo = t * per;
  const int hi = min(lo + per, NB);
  int s = 0;
  for (int i = lo; i < hi; ++i) s += count[i];
  lds[t] = s;
  __syncthreads();
  for (int d = 1; d < 1024; d <<= 1) {
    int v = (t >= d) ? lds[t - d] : 0;
    __syncthreads();
    lds[t] += v;
    __syncthreads();
  }
  int excl = lds[t] - s;
  for (int i = lo; i < hi; ++i) {
    offset[i] = excl;
    cursor[i] = excl;
    excl += count[i];
  }
  if (t == 1023) offset[NB] = lds[1023];
}

__global__ void scatter_kernel(const int* __restrict__ seg, int E,
                               int* __restrict__ cursor, int* __restrict__ order) {
  int e = blockIdx.x * blockDim.x + threadIdx.x;
  if (e >= E) return;
  int pos = atomicAdd(&cursor[seg[e]], 1);
  order[pos] = e;
}

// --------- fused per-segment edge LN: stats (gather) + output (scatter) -----
#define ELN_CAP 512
__global__ void edge_ln_kernel(const float4* __restrict__ EA4,
                               const float* __restrict__ wE,
                               const float* __restrict__ bE,
                               const int* __restrict__ offset,
                               const int* __restrict__ order,
                               float4* __restrict__ E_out4) {
  const int b = blockIdx.x;
  const int start = offset[b], end = offset[b + 1];
  const int cnt = end - start;
  const int fg = threadIdx.x & 15;    // feature group
  const int slot = threadIdx.x >> 4;  // 0..15 (4 slots per wave)
  const int wave = threadIdx.x >> 6;  // 0..3
  const int lane = threadIdx.x & 63;

  __shared__ int s_order[ELN_CAP];
  __shared__ float4 s_psum[4][16];
  __shared__ float4 s_psq[4][16];
  __shared__ float4 s_u[16], s_r[16];

  const int lim = min(cnt, ELN_CAP);
  for (int i = threadIdx.x; i < lim; i += 256) s_order[i] = order[start + i];
  __syncthreads();

  // --- stats: stride 16 slots, unroll x4 (covers 64 edges/sweep) ---
  float4 sum = f4zero(), sq = f4zero();
  for (int i = slot; i < cnt; i += 64) {
    int e0 = (i < ELN_CAP) ? s_order[i] : order[start + i];
    float4 x0 = EA4[(size_t)e0 * 16 + fg];
    float4 x1 = f4zero(), x2 = f4zero(), x3 = f4zero();
    if (i + 16 < cnt) {
      int e = (i + 16 < ELN_CAP) ? s_order[i + 16] : order[start + i + 16];
      x1 = EA4[(size_t)e * 16 + fg];
    }
    if (i + 32 < cnt) {
      int e = (i + 32 < ELN_CAP) ? s_order[i + 32] : order[start + i + 32];
      x2 = EA4[(size_t)e * 16 + fg];
    }
    if (i + 48 < cnt) {
      int e = (i + 48 < ELN_CAP) ? s_order[i + 48] : order[start + i + 48];
      x3 = EA4[(size_t)e * 16 + fg];
    }
    f4acc(sum, sq, x0); f4acc(sum, sq, x1); f4acc(sum, sq, x2); f4acc(sum, sq, x3);
  }
  // reduce 4 slots within wave (slot bits are lane bits 4,5)
  f4shflxor(sum, 16); f4shflxor(sum, 32);
  f4shflxor(sq, 16);  f4shflxor(sq, 32);
  if (lane < 16) { s_psum[wave][fg] = sum; s_psq[wave][fg] = sq; }
  __syncthreads();

  if (threadIdx.x < 16) {
    float4 ts = s_psum[0][fg], tq = s_psq[0][fg];
    f4add(ts, s_psum[1][fg]); f4add(ts, s_psum[2][fg]); f4add(ts, s_psum[3][fg]);
    f4add(tq, s_psq[1][fg]);  f4add(tq, s_psq[2][fg]);  f4add(tq, s_psq[3][fg]);
    const float dn = fmaxf((float)cnt, 1.0f);
    float4 u, r;
    u.x = ts.x / dn; u.y = ts.y / dn; u.z = ts.z / dn; u.w = ts.w / dn;
    r.x = rsqrtf(fmaxf(tq.x / dn - u.x * u.x, 0.f) + EPS_LN);
    r.y = rsqrtf(fmaxf(tq.y / dn - u.y * u.y, 0.f) + EPS_LN);
    r.z = rsqrtf(fmaxf(tq.z / dn - u.z * u.z, 0.f) + EPS_LN);
    r.w = rsqrtf(fmaxf(tq.w / dn - u.w * u.w, 0.f) + EPS_LN);
    s_u[fg] = u; s_r[fg] = r;
  }
  __syncthreads();

  // --- output: unroll x2, reads hit L2/L3 ---
  const float4 u = s_u[fg], r = s_r[fg];
  const float4 w = reinterpret_cast<const float4*>(wE)[fg];
  const float4 bb = reinterpret_cast<const float4*>(bE)[fg];
  for (int i = slot; i < cnt; i += 32) {
    int e0 = (i < ELN_CAP) ? s_order[i] : order[start + i];
    float4 x0 = EA4[(size_t)e0 * 16 + fg];
    const bool g1 = (i + 16) < cnt;
    int e1 = 0;
    float4 x1 = f4zero();
    if (g1) {
      e1 = (i + 16 < ELN_CAP) ? s_order[i + 16] : order[start + i + 16];
      x1 = EA4[(size_t)e1 * 16 + fg];
    }
    float4 o0;
    o0.x = fmaf(w.x * (x0.x - u.x), r.x, bb.x);
    o0.y = fmaf(w.y * (x0.y - u.y), r.y, bb.y);
    o0.z = fmaf(w.z * (x0.z - u.z), r.z, bb.z);
    o0.w = fmaf(w.w * (x0.w - u.w), r.w, bb.w);
    E_out4[(size_t)e0 * 16 + fg] = o0;
    if (g1) {
      float4 o1;
      o1.x = fmaf(w.x * (x1.x - u.x), r.x, bb.x);
      o1.y = fmaf(w.y * (x1.y - u.y), r.y, bb.y);
      o1.z = fmaf(w.z * (x1.z - u.z), r.z, bb.z);
      o1.w = fmaf(w.w * (x1.w - u.w), r.w, bb.w);
      E_out4[(size_t)e1 * 16 + fg] = o1;
    }
  }
}

extern "C" void kernel_launch(void* const* d_in, const int* in_sizes, int n_in,
                              void* d_out, int out_size, void* d_ws, size_t ws_size,
                              hipStream_t stream) {
  const float* H        = (const float*)d_in[0];
  const float* Z        = (const float*)d_in[1];
  const float* EA       = (const float*)d_in[2];
  const float* sigma    = (const float*)d_in[3];
  const float* ln_H_w   = (const float*)d_in[4];
  const float* ln_H_b   = (const float*)d_in[5];
  const float* ln_E_w   = (const float*)d_in[6];
  const float* ln_E_b   = (const float*)d_in[7];
  const int*   block_id = (const int*)d_in[8];
  const int*   edge_id  = (const int*)d_in[9];

  const int N = in_sizes[0] / 128;
  const int E = in_sizes[2] / 64;
  const int NB = (int)(((long long)out_size - (long long)N * 131 - (long long)E * 64) / 3);

  float* out = (float*)d_out;
  float* H_out = out;
  float* Z_out = out + (size_t)N * 128;
  float* E_out = out + (size_t)N * 128 + (size_t)N * 3;
  float* resc  = out + (size_t)N * 128 + (size_t)N * 3 + (size_t)E * 64;

  // workspace layout (ints)
  int* seg      = (int*)d_ws;        // E
  int* order    = seg + E;           // E
  int* count    = order + E;         // NB
  int* offset   = count + NB;        // NB+1
  int* cursor   = offset + NB + 1;   // NB
  int* node_off = cursor + NB;       // NB+1

  node_off_kernel<<<(N + 255) / 256, 256, 0, stream>>>(block_id, N, NB, node_off, count);
  edge_seg_kernel<<<(E + 255) / 256, 256, 0, stream>>>(edge_id, block_id, E, seg, count);
  node_kernel<<<NB, 256, 0, stream>>>((const float4*)H, Z, sigma, ln_H_w, ln_H_b,
                                      node_off, (float4*)H_out, Z_out, resc);
  scan_kernel<<<1, 1024, 0, stream>>>(count, NB, offset, cursor);
  scatter_kernel<<<(E + 255) / 256, 256, 0, stream>>>(seg, E, cursor, order);
  edge_ln_kernel<<<NB, 256, 0, stream>>>((const float4*)EA, ln_E_w, ln_E_b,
                                         offset, order, (float4*)E_out);
}

// Round 5
// 235.765 us; speedup vs baseline: 1.9612x; 1.3670x over previous
//
#include <hip/hip_runtime.h>
#include <hip/hip_bf16.h>

// EquivariantLayerNorm: segmented (per-block) LayerNorm over H and edge_attr,
// plus equivariant coordinate rescale on Z.
//
// Inputs (setup_inputs order, all f32 except ids):
//  0: H        [N,128]   1: Z       [N,3]    2: edge_attr [E,64]
//  3: sigma    [1,3]     4: ln_H_w  [128]    5: ln_H_b    [128]
//  6: ln_E_w   [64]      7: ln_E_b  [64]     8: block_id  [N] (sorted i32)
//  9: edge_id  [2,E] i32
// Output: concat(H_out [N*128], Z_out [N*3], E_out [E*64], rescale [NB*3])

#define EPS_LN 1e-12f
#define EPS_STD 1e-8f
#define ELN_CAP 512

typedef float f32x4_ev __attribute__((ext_vector_type(4)));

__device__ __forceinline__ float4 f4zero() { return make_float4(0.f, 0.f, 0.f, 0.f); }
__device__ __forceinline__ void f4acc(float4& s, float4& q, const float4 x) {
  s.x += x.x; s.y += x.y; s.z += x.z; s.w += x.w;
  q.x = fmaf(x.x, x.x, q.x); q.y = fmaf(x.y, x.y, q.y);
  q.z = fmaf(x.z, x.z, q.z); q.w = fmaf(x.w, x.w, q.w);
}
__device__ __forceinline__ void f4add(float4& a, const float4 b) {
  a.x += b.x; a.y += b.y; a.z += b.z; a.w += b.w;
}
__device__ __forceinline__ void f4shflxor(float4& v, int m) {
  v.x += __shfl_xor(v.x, m); v.y += __shfl_xor(v.y, m);
  v.z += __shfl_xor(v.z, m); v.w += __shfl_xor(v.w, m);
}
__device__ __forceinline__ void nt_store4(float4* p, const float4 v) {
  f32x4_ev t;
  t.x = v.x; t.y = v.y; t.z = v.z; t.w = v.w;
  __builtin_nontemporal_store(t, (f32x4_ev*)p);
}

// ---------- segment offsets from sorted block_id + zero counts --------------
__global__ void node_off_kernel(const int* __restrict__ block_id, int N, int NB,
                                int* __restrict__ node_off, int* __restrict__ count) {
  int i = blockIdx.x * blockDim.x + threadIdx.x;
  if (i < NB) count[i] = 0;
  if (i >= N) return;
  int cur = block_id[i];
  int prev = (i == 0) ? -1 : block_id[i - 1];
  for (int b = prev + 1; b <= cur; ++b) node_off[b] = i;
  if (i == N - 1) {
    for (int b = cur + 1; b <= NB; ++b) node_off[b] = N;
  }
}

// ---------- edge segment + rank (histogram) ---------------------------------
__global__ void edge_seg_kernel(const int* __restrict__ edge_id,
                                const int* __restrict__ block_id, int E,
                                int* __restrict__ seg, int* __restrict__ pos,
                                int* __restrict__ count) {
  int e = blockIdx.x * blockDim.x + threadIdx.x;
  if (e >= E) return;
  int s = block_id[edge_id[e]];  // row 0 of edge_id [2,E]
  seg[e] = s;
  pos[e] = atomicAdd(&count[s], 1);
}

__global__ void scan_kernel(const int* __restrict__ count, int NB,
                            int* __restrict__ offset) {
  __shared__ int lds[1024];
  const int t = threadIdx.x;
  const int per = (NB + 1023) / 1024;
  const int lo = t * per;
  const int hi = min(lo + per, NB);
  int s = 0;
  for (int i = lo; i < hi; ++i) s += count[i];
  lds[t] = s;
  __syncthreads();
  for (int d = 1; d < 1024; d <<= 1) {
    int v = (t >= d) ? lds[t - d] : 0;
    __syncthreads();
    lds[t] += v;
    __syncthreads();
  }
  int excl = lds[t] - s;
  for (int i = lo; i < hi; ++i) {
    offset[i] = excl;
    excl += count[i];
  }
  if (t == 1023) offset[NB] = lds[1023];
}

// ---------- atomic-free scatter ----------------------------------------------
__global__ void scatter_kernel(const int* __restrict__ seg,
                               const int* __restrict__ pos,
                               const int* __restrict__ offset, int E,
                               int* __restrict__ order) {
  int e = blockIdx.x * blockDim.x + threadIdx.x;
  if (e >= E) return;
  order[offset[seg[e]] + pos[e]] = e;
}

// ---------------- fused compute: edge LN (b < NB) + node work (b >= NB) -----
struct EdgeSmem {
  int order[ELN_CAP];
  float4 psum[4][16];
  float4 psq[4][16];
  float4 u[16], r[16];
};
struct NodeSmem {
  float4 psum[4][32];
  float4 psq[4][32];
  float4 u[32], r[32];
  float zp[64], zq[64];
  float zc[3], resc[3];
};
union MainSmem { EdgeSmem e; NodeSmem n; };

__global__ void main_kernel(const float4* __restrict__ H4,
                            const float* __restrict__ Z,
                            const float* __restrict__ sigma,
                            const float* __restrict__ wH,
                            const float* __restrict__ bH,
                            const int* __restrict__ node_off,
                            float4* __restrict__ H_out4,
                            float* __restrict__ Z_out,
                            float* __restrict__ rescale_out,
                            const float4* __restrict__ EA4,
                            const float* __restrict__ wE,
                            const float* __restrict__ bE,
                            const int* __restrict__ offset,
                            const int* __restrict__ order,
                            float4* __restrict__ E_out4,
                            int NB) {
  __shared__ MainSmem sm;
  const int wave = threadIdx.x >> 6;
  const int lane = threadIdx.x & 63;

  if (blockIdx.x < NB) {
    // ======================= EDGE SEGMENT ===================================
    const int b = blockIdx.x;
    const int start = offset[b], end = offset[b + 1];
    const int cnt = end - start;
    const int fg = threadIdx.x & 15;    // feature group (floats fg*4..fg*4+3)
    const int slot = threadIdx.x >> 4;  // 0..15

    const bool fits = (cnt <= ELN_CAP);
    const int lim = fits ? cnt : ELN_CAP;
    for (int i = threadIdx.x; i < lim; i += 256) sm.e.order[i] = order[start + i];
    __syncthreads();

    // --- stats: unroll x8 (128 edges in flight per sweep) ---
    float4 sum = f4zero(), sq = f4zero();
    if (fits) {
      for (int i = slot; i < cnt; i += 128) {
        float4 x[8];
        #pragma unroll
        for (int k = 0; k < 8; ++k) {
          const int ii = i + k * 16;
          x[k] = (ii < cnt) ? EA4[(size_t)sm.e.order[ii] * 16 + fg] : f4zero();
        }
        #pragma unroll
        for (int k = 0; k < 8; ++k) f4acc(sum, sq, x[k]);
      }
    } else {
      for (int i = slot; i < cnt; i += 16) {
        int e = (i < ELN_CAP) ? sm.e.order[i] : order[start + i];
        f4acc(sum, sq, EA4[(size_t)e * 16 + fg]);
      }
    }
    f4shflxor(sum, 16); f4shflxor(sum, 32);
    f4shflxor(sq, 16);  f4shflxor(sq, 32);
    if (lane < 16) { sm.e.psum[wave][fg] = sum; sm.e.psq[wave][fg] = sq; }
    __syncthreads();

    if (threadIdx.x < 16) {
      float4 ts = sm.e.psum[0][fg], tq = sm.e.psq[0][fg];
      f4add(ts, sm.e.psum[1][fg]); f4add(ts, sm.e.psum[2][fg]); f4add(ts, sm.e.psum[3][fg]);
      f4add(tq, sm.e.psq[1][fg]);  f4add(tq, sm.e.psq[2][fg]);  f4add(tq, sm.e.psq[3][fg]);
      const float dn = fmaxf((float)cnt, 1.0f);
      float4 u, r;
      u.x = ts.x / dn; u.y = ts.y / dn; u.z = ts.z / dn; u.w = ts.w / dn;
      r.x = rsqrtf(fmaxf(tq.x / dn - u.x * u.x, 0.f) + EPS_LN);
      r.y = rsqrtf(fmaxf(tq.y / dn - u.y * u.y, 0.f) + EPS_LN);
      r.z = rsqrtf(fmaxf(tq.z / dn - u.z * u.z, 0.f) + EPS_LN);
      r.w = rsqrtf(fmaxf(tq.w / dn - u.w * u.w, 0.f) + EPS_LN);
      sm.e.u[fg] = u; sm.e.r[fg] = r;
    }
    __syncthreads();

    // --- output: load 4 rows, then store 4 (reads mostly L2-hit) ---
    const float4 u = sm.e.u[fg], r = sm.e.r[fg];
    const float4 w = reinterpret_cast<const float4*>(wE)[fg];
    const float4 bb = reinterpret_cast<const float4*>(bE)[fg];
    if (fits) {
      for (int i = slot; i < cnt; i += 64) {
        int e[4];
        float4 x[4];
        #pragma unroll
        for (int k = 0; k < 4; ++k) {
          const int ii = i + k * 16;
          if (ii < cnt) {
            e[k] = sm.e.order[ii];
            x[k] = EA4[(size_t)e[k] * 16 + fg];
          } else e[k] = -1;
        }
        #pragma unroll
        for (int k = 0; k < 4; ++k) {
          if (e[k] >= 0) {
            float4 o;
            o.x = fmaf(w.x * (x[k].x - u.x), r.x, bb.x);
            o.y = fmaf(w.y * (x[k].y - u.y), r.y, bb.y);
            o.z = fmaf(w.z * (x[k].z - u.z), r.z, bb.z);
            o.w = fmaf(w.w * (x[k].w - u.w), r.w, bb.w);
            nt_store4(&E_out4[(size_t)e[k] * 16 + fg], o);
          }
        }
      }
    } else {
      for (int i = slot; i < cnt; i += 16) {
        int e = (i < ELN_CAP) ? sm.e.order[i] : order[start + i];
        float4 x = EA4[(size_t)e * 16 + fg];
        float4 o;
        o.x = fmaf(w.x * (x.x - u.x), r.x, bb.x);
        o.y = fmaf(w.y * (x.y - u.y), r.y, bb.y);
        o.z = fmaf(w.z * (x.z - u.z), r.z, bb.z);
        o.w = fmaf(w.w * (x.w - u.w), r.w, bb.w);
        nt_store4(&E_out4[(size_t)e * 16 + fg], o);
      }
    }
  } else {
    // ======================= NODE SEGMENT ===================================
    const int b = blockIdx.x - NB;
    const int start = node_off[b], end = node_off[b + 1];
    const int c = end - start;
    const float denom = fmaxf((float)c, 1.0f);
    const int fg = threadIdx.x & 31;    // feature group
    const int slot = threadIdx.x >> 5;  // 0..7

    // --- H stats: stride 8 slots, unroll x3 ---
    float4 sum = f4zero(), sq = f4zero();
    for (int i = start + slot; i < end; i += 24) {
      float4 x0 = H4[(size_t)i * 32 + fg];
      float4 x1 = (i + 8  < end) ? H4[(size_t)(i + 8)  * 32 + fg] : f4zero();
      float4 x2 = (i + 16 < end) ? H4[(size_t)(i + 16) * 32 + fg] : f4zero();
      f4acc(sum, sq, x0); f4acc(sum, sq, x1); f4acc(sum, sq, x2);
    }
    f4shflxor(sum, 32); f4shflxor(sq, 32);
    if (lane < 32) { sm.n.psum[wave][fg] = sum; sm.n.psq[wave][fg] = sq; }

    // --- Z single-pass stats: wave 3, 63 coalesced lanes ---
    if (wave == 3 && lane < 63) {
      const float* zbase = Z + (size_t)start * 3;
      const int tot = c * 3;
      float zs = 0.f, zq = 0.f;
      for (int j = lane; j < tot; j += 63) {  // 63 % 3 == 0 -> axis fixed
        float z = zbase[j];
        zs += z; zq = fmaf(z, z, zq);
      }
      sm.n.zp[lane] = zs; sm.n.zq[lane] = zq;
    }
    __syncthreads();

    if (threadIdx.x < 32) {
      float4 ts = sm.n.psum[0][fg], tq = sm.n.psq[0][fg];
      f4add(ts, sm.n.psum[1][fg]); f4add(ts, sm.n.psum[2][fg]); f4add(ts, sm.n.psum[3][fg]);
      f4add(tq, sm.n.psq[1][fg]);  f4add(tq, sm.n.psq[2][fg]);  f4add(tq, sm.n.psq[3][fg]);
      float4 u, r;
      u.x = ts.x / denom; u.y = ts.y / denom; u.z = ts.z / denom; u.w = ts.w / denom;
      r.x = rsqrtf(fmaxf(tq.x / denom - u.x * u.x, 0.f) + EPS_LN);
      r.y = rsqrtf(fmaxf(tq.y / denom - u.y * u.y, 0.f) + EPS_LN);
      r.z = rsqrtf(fmaxf(tq.z / denom - u.z * u.z, 0.f) + EPS_LN);
      r.w = rsqrtf(fmaxf(tq.w / denom - u.w * u.w, 0.f) + EPS_LN);
      sm.n.u[fg] = u; sm.n.r[fg] = r;
    }
    if (threadIdx.x == 64) {
      float zs[3], zq[3];
      #pragma unroll
      for (int a = 0; a < 3; ++a) {
        float ps = 0.f, pq = 0.f;
        for (int k = a; k < 63; k += 3) { ps += sm.n.zp[k]; pq += sm.n.zq[k]; }
        zs[a] = ps; zq[a] = pq;
      }
      const float cnt3 = 3.0f * (float)c;
      float msum = 0.f, ss = 0.f;
      #pragma unroll
      for (int a = 0; a < 3; ++a) {
        float zc = zs[a] / denom;
        sm.n.zc[a] = zc;
        msum += zs[a] - (float)c * zc;
        ss += zq[a] - 2.f * zc * zs[a] + (float)c * zc * zc;
      }
      const float m = msum / fmaxf(cnt3, 1.0f);
      ss = fmaxf(ss - cnt3 * m * m, 0.f);
      const float var_Ez = sqrtf(ss / fmaxf(cnt3 - 1.0f, 1.0f)) + EPS_STD;
      #pragma unroll
      for (int a = 0; a < 3; ++a) {
        float rc = sigma[a] / var_Ez;
        sm.n.resc[a] = rc;
        rescale_out[(size_t)b * 3 + a] = rc;
      }
    }
    __syncthreads();

    // --- H output pass ---
    {
      const float4 u = sm.n.u[fg], r = sm.n.r[fg];
      const float4 w = reinterpret_cast<const float4*>(wH)[fg];
      const float4 bb = reinterpret_cast<const float4*>(bH)[fg];
      for (int i = start + slot; i < end; i += 24) {
        #pragma unroll
        for (int k = 0; k < 3; ++k) {
          int ii = i + k * 8;
          if (ii < end) {
            float4 x = H4[(size_t)ii * 32 + fg];
            float4 o;
            o.x = fmaf(w.x * (x.x - u.x), r.x, bb.x);
            o.y = fmaf(w.y * (x.y - u.y), r.y, bb.y);
            o.z = fmaf(w.z * (x.z - u.z), r.z, bb.z);
            o.w = fmaf(w.w * (x.w - u.w), r.w, bb.w);
            nt_store4(&H_out4[(size_t)ii * 32 + fg], o);
          }
        }
      }
    }

    // --- Z output (wave 3, coalesced) ---
    if (wave == 3 && lane < 63) {
      const float* zbase = Z + (size_t)start * 3;
      float* zobase = Z_out + (size_t)start * 3;
      const int tot = c * 3;
      const int a = lane % 3;
      const float zc = sm.n.zc[a], rc = sm.n.resc[a];
      for (int j = lane; j < tot; j += 63) {
        float z = zbase[j];
        __builtin_nontemporal_store(fmaf(z - zc, rc, zc), &zobase[j]);
      }
    }
  }
}

extern "C" void kernel_launch(void* const* d_in, const int* in_sizes, int n_in,
                              void* d_out, int out_size, void* d_ws, size_t ws_size,
                              hipStream_t stream) {
  const float* H        = (const float*)d_in[0];
  const float* Z        = (const float*)d_in[1];
  const float* EA       = (const float*)d_in[2];
  const float* sigma    = (const float*)d_in[3];
  const float* ln_H_w   = (const float*)d_in[4];
  const float* ln_H_b   = (const float*)d_in[5];
  const float* ln_E_w   = (const float*)d_in[6];
  const float* ln_E_b   = (const float*)d_in[7];
  const int*   block_id = (const int*)d_in[8];
  const int*   edge_id  = (const int*)d_in[9];

  const int N = in_sizes[0] / 128;
  const int E = in_sizes[2] / 64;
  const int NB = (int)(((long long)out_size - (long long)N * 131 - (long long)E * 64) / 3);

  float* out = (float*)d_out;
  float* H_out = out;
  float* Z_out = out + (size_t)N * 128;
  float* E_out = out + (size_t)N * 128 + (size_t)N * 3;
  float* resc  = out + (size_t)N * 128 + (size_t)N * 3 + (size_t)E * 64;

  // workspace layout (ints)
  int* seg      = (int*)d_ws;        // E
  int* pos      = seg + E;           // E
  int* order    = pos + E;           // E
  int* count    = order + E;         // NB
  int* offset   = count + NB;        // NB+1
  int* node_off = offset + NB + 1;   // NB+1

  node_off_kernel<<<(N + 255) / 256, 256, 0, stream>>>(block_id, N, NB, node_off, count);
  edge_seg_kernel<<<(E + 255) / 256, 256, 0, stream>>>(edge_id, block_id, E, seg, pos, count);
  scan_kernel<<<1, 1024, 0, stream>>>(count, NB, offset);
  scatter_kernel<<<(E + 255) / 256, 256, 0, stream>>>(seg, pos, offset, E, order);
  main_kernel<<<2 * NB, 256, 0, stream>>>((const float4*)H, Z, sigma, ln_H_w, ln_H_b,
                                          node_off, (float4*)H_out, Z_out, resc,
                                          (const float4*)EA, ln_E_w, ln_E_b,
                                          offset, order, (float4*)E_out, NB);
}